// Round 9
// baseline (292.018 us; speedup 1.0000x reference)
//
#include <hip/hip_runtime.h>
#include <hip/hip_bf16.h>

// GCN block: 3 x { t = relu(h @ W^T); h' = A_coo @ t (per sample) }
// B=8, N=10000, D=64, E=160000.
//
// Round 9:
//  - SpMM reverted to round-6 shape (wave per row, full 512-bf16 row as
//    uint4/lane, unroll 4, no cross-lane reduction). Rounds 7/8 proved
//    feature-slicing loses ~45-60us to divergence/shallow loops.
//  - NEW: edges ordered by (row, col_tile) with 4 col-tiles of 2500 nodes.
//    SpMM loop is unchanged, but all waves progress tile-by-tile in rough
//    lockstep -> instantaneous gather working set ~2.56MB <= 4MB per-XCD L2
//    (t table is 10.24MB; round-5/6 counters showed ~6.5x HBM re-fetch).
//    CSR build keyed on r*4+tile; scan over 40001 entries via one
//    1024-thread block (no LDS staging of counts).
//  - zero_kernel for cnt (in-graph fillBufferAligned measured 43us/40KB).
//  - gemm_relu_lds unchanged (LDS-staged h tile, W in VGPRs, bf16 stores).

#define GCN_B 8
#define GCN_N 10000
#define GCN_D 64
#define GCN_E 160000
#define GCN_BN (GCN_B * GCN_N)
#define GCN_T 4                 // col tiles
#define GCN_M (GCN_N * GCN_T)   // keyed counters

// ---------------- GEMM + ReLU (LDS-staged, bf16 out) ----------------
__global__ __launch_bounds__(256) void gemm_relu_lds(
    const float* __restrict__ h,
    const float* __restrict__ W,        // [64,64]; out[f] = sum_d h[d]*W[f*64+d]
    __hip_bfloat16* __restrict__ t,     // [N][B][64] bf16 flat
    int permute_in)
{
    __shared__ float hs[64 * 64];  // 16 KB

    const int tid = threadIdx.x;
    const int f = tid & 63;
    const int w = tid >> 6;
    const int g0 = blockIdx.x * 64;

    float4* hs4w = reinterpret_cast<float4*>(hs);
#pragma unroll
    for (int k = 0; k < 4; ++k) {
        int q = k * 256 + tid;
        int row = q >> 4;
        int c4 = q & 15;
        int g = g0 + row;
        const float4* src;
        if (permute_in) {
            int n = g >> 3, b = g & 7;
            src = reinterpret_cast<const float4*>(h + ((size_t)b * GCN_N + n) * 64) + c4;
        } else {
            src = reinterpret_cast<const float4*>(h + (size_t)g * 64) + c4;
        }
        hs4w[q] = *src;
    }

    float4 wr[16];
    const float4* W4 = reinterpret_cast<const float4*>(W);
#pragma unroll
    for (int i = 0; i < 16; ++i) wr[i] = W4[f * 16 + i];

    __syncthreads();

    const float4* hs4 = reinterpret_cast<const float4*>(hs);
#pragma unroll 4
    for (int rr = 0; rr < 16; ++rr) {
        const int row = w * 16 + rr;
        float acc = 0.f;
#pragma unroll
        for (int i = 0; i < 16; ++i) {
            float4 v = hs4[row * 16 + i];
            acc += v.x * wr[i].x + v.y * wr[i].y + v.z * wr[i].z + v.w * wr[i].w;
        }
        t[(size_t)(g0 + row) * 64 + f] = __float2bfloat16(fmaxf(acc, 0.0f));
    }
}

// ---------------- CSR build (keyed on row*4 + col_tile) ----------------
__global__ __launch_bounds__(256) void zero_kernel(int* __restrict__ p, int n)
{
    int i = blockIdx.x * 256 + threadIdx.x;
    if (i < n) p[i] = 0;
}

__global__ __launch_bounds__(256) void hist_kernel(
    const int* __restrict__ rows, const int* __restrict__ cols,
    int* __restrict__ cnt, int E)
{
    int e = blockIdx.x * 256 + threadIdx.x;
    if (e >= E) return;
    int tile = (unsigned)cols[e] / 2500u;          // 0..3
    atomicAdd(&cnt[rows[e] * GCN_T + tile], 1);
}

// Single 1024-thread block; scans 40000 counters straight from global.
__global__ __launch_bounds__(1024) void scan_kernel(
    const int* __restrict__ cnt, int* __restrict__ rp, int* __restrict__ cur)
{
    __shared__ int part[1024];
    const int tid = threadIdx.x;
    const int per = (GCN_M + 1023) / 1024;   // 40
    const int base = tid * per;

    int s = 0;
    for (int i = 0; i < per; ++i) {
        int idx = base + i;
        if (idx < GCN_M) s += cnt[idx];
    }
    part[tid] = s;
    __syncthreads();
    for (int off = 1; off < 1024; off <<= 1) {
        int add = (tid >= off) ? part[tid - off] : 0;
        __syncthreads();
        part[tid] += add;
        __syncthreads();
    }
    int run = part[tid] - s;                 // exclusive prefix of this segment
    for (int i = 0; i < per; ++i) {
        int idx = base + i;
        if (idx < GCN_M) {
            int c = cnt[idx];
            rp[idx] = run;
            cur[idx] = run;
            run += c;
        }
    }
    if (tid == 0) rp[GCN_M] = GCN_E;
}

__global__ __launch_bounds__(256) void scatter_kernel(
    const float* __restrict__ vals, const int* __restrict__ rows,
    const int* __restrict__ cols, int* __restrict__ cur,
    float* __restrict__ pval, int* __restrict__ pcol, int E)
{
    int e = blockIdx.x * 256 + threadIdx.x;
    if (e >= E) return;
    int c = cols[e];
    int tile = (unsigned)c / 2500u;
    int pos = atomicAdd(&cur[rows[e] * GCN_T + tile], 1);
    pval[pos] = vals[e];
    pcol[pos] = c;
}

// ---------------- CSR SpMM (bf16 gather, f32 accumulate) ----------------
// t is [N][512] bf16 = [N][64] uint4. Lane holds elements [lane*8, lane*8+8):
// b = lane>>3, d0 = (lane&7)*8. Edges are col-tile-ordered within each row.
__global__ __launch_bounds__(256) void spmm_csr_bf16(
    const uint4* __restrict__ t4,      // [N*64]
    const float* __restrict__ pval,
    const int* __restrict__ pcol,
    const int* __restrict__ rp,        // [N*4+1]
    float* __restrict__ out,
    int final_layout)                  // 0: out [n][512]; 1: out [b][n][64]
{
    const int r = (blockIdx.x * 256 + threadIdx.x) >> 6;
    const int lane = threadIdx.x & 63;
    if (r >= GCN_N) return;

    const int beg = rp[r * GCN_T];
    const int end = rp[r * GCN_T + GCN_T];

    float a[8];
#pragma unroll
    for (int i = 0; i < 8; ++i) a[i] = 0.f;

#pragma unroll 4
    for (int j = beg; j < end; ++j) {
        const float v = pval[j];                  // broadcast
        const int c = pcol[j];                    // broadcast
        uint4 u = t4[(size_t)c * 64 + lane];      // coalesced 1KB row gather
        a[0] += v * __uint_as_float(u.x << 16);
        a[1] += v * __uint_as_float(u.x & 0xffff0000u);
        a[2] += v * __uint_as_float(u.y << 16);
        a[3] += v * __uint_as_float(u.y & 0xffff0000u);
        a[4] += v * __uint_as_float(u.z << 16);
        a[5] += v * __uint_as_float(u.z & 0xffff0000u);
        a[6] += v * __uint_as_float(u.w << 16);
        a[7] += v * __uint_as_float(u.w & 0xffff0000u);
    }

    const int b = lane >> 3;
    const int d0 = (lane & 7) * 8;
    float* op;
    if (!final_layout) op = out + (size_t)r * 512 + b * 64 + d0;
    else               op = out + ((size_t)b * GCN_N + r) * 64 + d0;
    *reinterpret_cast<float4*>(op)     = make_float4(a[0], a[1], a[2], a[3]);
    *reinterpret_cast<float4*>(op + 4) = make_float4(a[4], a[5], a[6], a[7]);
}

extern "C" void kernel_launch(void* const* d_in, const int* in_sizes, int n_in,
                              void* d_out, int out_size, void* d_ws, size_t ws_size,
                              hipStream_t stream) {
    const float* x    = (const float*)d_in[0];
    const float* W0   = (const float*)d_in[1];
    const float* W1   = (const float*)d_in[2];
    const float* W2   = (const float*)d_in[3];
    const float* vals = (const float*)d_in[4];
    const int*   rows = (const int*)d_in[5];
    const int*   cols = (const int*)d_in[6];
    float* out = (float*)d_out;

    const size_t t_bytes = (size_t)GCN_BN * GCN_D * sizeof(__hip_bfloat16); // 10,240,000

    char* ws = (char*)d_ws;
    __hip_bfloat16* t = (__hip_bfloat16*)ws;
    size_t off = (t_bytes + 255) / 256 * 256;
    int*   rp   = (int*)(ws + off); off += ((GCN_M + 1) * 4 + 255) / 256 * 256;
    int*   cur  = (int*)(ws + off); off += (GCN_M * 4 + 255) / 256 * 256;
    int*   cnt  = (int*)(ws + off); off += (GCN_M * 4 + 255) / 256 * 256;
    float* pval = (float*)(ws + off); off += GCN_E * 4;
    int*   pcol = (int*)(ws + off); off += GCN_E * 4;

    const int gemm_grid = GCN_BN / 64;                // 1250 tiles
    const int edge_grid = (GCN_E + 255) / 256;        // 625
    const int spmm_grid = (GCN_N * 64 + 255) / 256;   // 2500 (wave per row)

    // Build col-tile-ordered CSR once; reused by all 3 layers.
    zero_kernel<<<(GCN_M + 255) / 256, 256, 0, stream>>>(cnt, GCN_M);
    hist_kernel<<<edge_grid, 256, 0, stream>>>(rows, cols, cnt, GCN_E);
    scan_kernel<<<1, 1024, 0, stream>>>(cnt, rp, cur);
    scatter_kernel<<<edge_grid, 256, 0, stream>>>(vals, rows, cols, cur, pval, pcol, GCN_E);

    const uint4* t4 = (const uint4*)t;

    // layer 1: x is [b][n][64] -> permuted read; intermediates in [n][512]
    gemm_relu_lds<<<gemm_grid, 256, 0, stream>>>(x, W0, t, 1);
    spmm_csr_bf16<<<spmm_grid, 256, 0, stream>>>(t4, pval, pcol, rp, out, 0);

    // layer 2
    gemm_relu_lds<<<gemm_grid, 256, 0, stream>>>(out, W1, t, 0);
    spmm_csr_bf16<<<spmm_grid, 256, 0, stream>>>(t4, pval, pcol, rp, out, 0);

    // layer 3: final output in [b][n][64]
    gemm_relu_lds<<<gemm_grid, 256, 0, stream>>>(out, W2, t, 0);
    spmm_csr_bf16<<<spmm_grid, 256, 0, stream>>>(t4, pval, pcol, rp, out, 1);
}

// Round 10
// 200.640 us; speedup vs baseline: 1.4554x; 1.4554x over previous
//
#include <hip/hip_runtime.h>
#include <hip/hip_bf16.h>

// GCN block: 3 x { t = relu(h @ W^T); h' = A_coo @ t (per sample) }
// B=8, N=10000, D=64, E=160000.
//
// Round 10:
//  - scan fixed: round-9's single-block direct-global scan measured 101us
//    (3 serial passes x 40 uncoalesced loads). Now hierarchical:
//    scan1 (40 blocks, LDS-staged 1024-entry block scans) -> scan2 (one
//    wave scans 40 block sums) -> scan3 (add offsets, fill cur). ~10us.
//  - Everything else IDENTICAL to round 9 so spmm FETCH_SIZE cleanly tests
//    the col-tile-ordered-edges hypothesis (per-XCD L2 working set 2.56MB).
//  - SpMM: wave per row, 512-bf16 row as uint4/lane, unroll 4.
//  - zero_kernel for cnt; gemm_relu_lds (LDS h tile, W in VGPRs, bf16 out).

#define GCN_B 8
#define GCN_N 10000
#define GCN_D 64
#define GCN_E 160000
#define GCN_BN (GCN_B * GCN_N)
#define GCN_T 4                 // col tiles
#define GCN_M (GCN_N * GCN_T)   // keyed counters
#define SCAN_BLKS ((GCN_M + 1023) / 1024)   // 40

// ---------------- GEMM + ReLU (LDS-staged, bf16 out) ----------------
__global__ __launch_bounds__(256) void gemm_relu_lds(
    const float* __restrict__ h,
    const float* __restrict__ W,        // [64,64]; out[f] = sum_d h[d]*W[f*64+d]
    __hip_bfloat16* __restrict__ t,     // [N][B][64] bf16 flat
    int permute_in)
{
    __shared__ float hs[64 * 64];  // 16 KB

    const int tid = threadIdx.x;
    const int f = tid & 63;
    const int w = tid >> 6;
    const int g0 = blockIdx.x * 64;

    float4* hs4w = reinterpret_cast<float4*>(hs);
#pragma unroll
    for (int k = 0; k < 4; ++k) {
        int q = k * 256 + tid;
        int row = q >> 4;
        int c4 = q & 15;
        int g = g0 + row;
        const float4* src;
        if (permute_in) {
            int n = g >> 3, b = g & 7;
            src = reinterpret_cast<const float4*>(h + ((size_t)b * GCN_N + n) * 64) + c4;
        } else {
            src = reinterpret_cast<const float4*>(h + (size_t)g * 64) + c4;
        }
        hs4w[q] = *src;
    }

    float4 wr[16];
    const float4* W4 = reinterpret_cast<const float4*>(W);
#pragma unroll
    for (int i = 0; i < 16; ++i) wr[i] = W4[f * 16 + i];

    __syncthreads();

    const float4* hs4 = reinterpret_cast<const float4*>(hs);
#pragma unroll 4
    for (int rr = 0; rr < 16; ++rr) {
        const int row = w * 16 + rr;
        float acc = 0.f;
#pragma unroll
        for (int i = 0; i < 16; ++i) {
            float4 v = hs4[row * 16 + i];
            acc += v.x * wr[i].x + v.y * wr[i].y + v.z * wr[i].z + v.w * wr[i].w;
        }
        t[(size_t)(g0 + row) * 64 + f] = __float2bfloat16(fmaxf(acc, 0.0f));
    }
}

// ---------------- CSR build (keyed on row*4 + col_tile) ----------------
__global__ __launch_bounds__(256) void zero_kernel(int* __restrict__ p, int n)
{
    int i = blockIdx.x * 256 + threadIdx.x;
    if (i < n) p[i] = 0;
}

__global__ __launch_bounds__(256) void hist_kernel(
    const int* __restrict__ rows, const int* __restrict__ cols,
    int* __restrict__ cnt, int E)
{
    int e = blockIdx.x * 256 + threadIdx.x;
    if (e >= E) return;
    int tile = (unsigned)cols[e] / 2500u;          // 0..3
    atomicAdd(&cnt[rows[e] * GCN_T + tile], 1);
}

// scan1: block b scans cnt[b*1024 .. b*1024+1024) -> exclusive prefixes in rp,
// block total in bsum[b]. Coalesced loads via LDS.
__global__ __launch_bounds__(256) void scan1_kernel(
    const int* __restrict__ cnt, int* __restrict__ rp, int* __restrict__ bsum)
{
    __shared__ int s[1024];
    __shared__ int part[256];
    const int tid = threadIdx.x;
    const int base = blockIdx.x * 1024;

#pragma unroll
    for (int k = 0; k < 4; ++k) {
        int idx = base + k * 256 + tid;
        s[k * 256 + tid] = (idx < GCN_M) ? cnt[idx] : 0;
    }
    __syncthreads();

    int l0 = s[tid * 4 + 0], l1 = s[tid * 4 + 1];
    int l2 = s[tid * 4 + 2], l3 = s[tid * 4 + 3];
    int ls = l0 + l1 + l2 + l3;
    part[tid] = ls;
    __syncthreads();
    for (int off = 1; off < 256; off <<= 1) {
        int add = (tid >= off) ? part[tid - off] : 0;
        __syncthreads();
        part[tid] += add;
        __syncthreads();
    }
    int run = part[tid] - ls;          // exclusive prefix of this 4-segment
    s[tid * 4 + 0] = run; run += l0;
    s[tid * 4 + 1] = run; run += l1;
    s[tid * 4 + 2] = run; run += l2;
    s[tid * 4 + 3] = run;
    if (tid == 255) bsum[blockIdx.x] = part[255];
    __syncthreads();

#pragma unroll
    for (int k = 0; k < 4; ++k) {
        int idx = base + k * 256 + tid;
        if (idx < GCN_M) rp[idx] = s[k * 256 + tid];
    }
}

// scan2: one wave turns bsum[0..nb) into its exclusive scan.
__global__ __launch_bounds__(64) void scan2_kernel(int* __restrict__ bsum, int nb)
{
    const int tid = threadIdx.x;
    int x = (tid < nb) ? bsum[tid] : 0;
    int v = x;
    for (int off = 1; off < 64; off <<= 1) {
        int u = __shfl_up(v, off, 64);
        if (tid >= off) v += u;
    }
    if (tid < nb) bsum[tid] = v - x;   // exclusive
}

// scan3: rp[idx] += bsum[block]; cur = rp; sentinel.
__global__ __launch_bounds__(256) void scan3_kernel(
    int* __restrict__ rp, int* __restrict__ cur, const int* __restrict__ bsum)
{
    const int base = blockIdx.x * 1024;
    const int off = bsum[blockIdx.x];
#pragma unroll
    for (int k = 0; k < 4; ++k) {
        int idx = base + k * 256 + threadIdx.x;
        if (idx < GCN_M) {
            int v = rp[idx] + off;
            rp[idx] = v;
            cur[idx] = v;
        }
    }
    if (blockIdx.x == 0 && threadIdx.x == 0) rp[GCN_M] = GCN_E;
}

__global__ __launch_bounds__(256) void scatter_kernel(
    const float* __restrict__ vals, const int* __restrict__ rows,
    const int* __restrict__ cols, int* __restrict__ cur,
    float* __restrict__ pval, int* __restrict__ pcol, int E)
{
    int e = blockIdx.x * 256 + threadIdx.x;
    if (e >= E) return;
    int c = cols[e];
    int tile = (unsigned)c / 2500u;
    int pos = atomicAdd(&cur[rows[e] * GCN_T + tile], 1);
    pval[pos] = vals[e];
    pcol[pos] = c;
}

// ---------------- CSR SpMM (bf16 gather, f32 accumulate) ----------------
// t is [N][512] bf16 = [N][64] uint4. Lane holds elements [lane*8, lane*8+8):
// b = lane>>3, d0 = (lane&7)*8. Edges are col-tile-ordered within each row.
__global__ __launch_bounds__(256) void spmm_csr_bf16(
    const uint4* __restrict__ t4,      // [N*64]
    const float* __restrict__ pval,
    const int* __restrict__ pcol,
    const int* __restrict__ rp,        // [N*4+1]
    float* __restrict__ out,
    int final_layout)                  // 0: out [n][512]; 1: out [b][n][64]
{
    const int r = (blockIdx.x * 256 + threadIdx.x) >> 6;
    const int lane = threadIdx.x & 63;
    if (r >= GCN_N) return;

    const int beg = rp[r * GCN_T];
    const int end = rp[r * GCN_T + GCN_T];

    float a[8];
#pragma unroll
    for (int i = 0; i < 8; ++i) a[i] = 0.f;

#pragma unroll 4
    for (int j = beg; j < end; ++j) {
        const float v = pval[j];                  // broadcast
        const int c = pcol[j];                    // broadcast
        uint4 u = t4[(size_t)c * 64 + lane];      // coalesced 1KB row gather
        a[0] += v * __uint_as_float(u.x << 16);
        a[1] += v * __uint_as_float(u.x & 0xffff0000u);
        a[2] += v * __uint_as_float(u.y << 16);
        a[3] += v * __uint_as_float(u.y & 0xffff0000u);
        a[4] += v * __uint_as_float(u.z << 16);
        a[5] += v * __uint_as_float(u.z & 0xffff0000u);
        a[6] += v * __uint_as_float(u.w << 16);
        a[7] += v * __uint_as_float(u.w & 0xffff0000u);
    }

    const int b = lane >> 3;
    const int d0 = (lane & 7) * 8;
    float* op;
    if (!final_layout) op = out + (size_t)r * 512 + b * 64 + d0;
    else               op = out + ((size_t)b * GCN_N + r) * 64 + d0;
    *reinterpret_cast<float4*>(op)     = make_float4(a[0], a[1], a[2], a[3]);
    *reinterpret_cast<float4*>(op + 4) = make_float4(a[4], a[5], a[6], a[7]);
}

extern "C" void kernel_launch(void* const* d_in, const int* in_sizes, int n_in,
                              void* d_out, int out_size, void* d_ws, size_t ws_size,
                              hipStream_t stream) {
    const float* x    = (const float*)d_in[0];
    const float* W0   = (const float*)d_in[1];
    const float* W1   = (const float*)d_in[2];
    const float* W2   = (const float*)d_in[3];
    const float* vals = (const float*)d_in[4];
    const int*   rows = (const int*)d_in[5];
    const int*   cols = (const int*)d_in[6];
    float* out = (float*)d_out;

    const size_t t_bytes = (size_t)GCN_BN * GCN_D * sizeof(__hip_bfloat16); // 10,240,000

    char* ws = (char*)d_ws;
    __hip_bfloat16* t = (__hip_bfloat16*)ws;
    size_t off = (t_bytes + 255) / 256 * 256;
    int*   rp   = (int*)(ws + off); off += ((GCN_M + 1) * 4 + 255) / 256 * 256;
    int*   cur  = (int*)(ws + off); off += (GCN_M * 4 + 255) / 256 * 256;
    int*   cnt  = (int*)(ws + off); off += (GCN_M * 4 + 255) / 256 * 256;
    int*   bsum = (int*)(ws + off); off += (SCAN_BLKS * 4 + 255) / 256 * 256;
    float* pval = (float*)(ws + off); off += GCN_E * 4;
    int*   pcol = (int*)(ws + off); off += GCN_E * 4;

    const int gemm_grid = GCN_BN / 64;                // 1250 tiles
    const int edge_grid = (GCN_E + 255) / 256;        // 625
    const int spmm_grid = (GCN_N * 64 + 255) / 256;   // 2500 (wave per row)

    // Build col-tile-ordered CSR once; reused by all 3 layers.
    zero_kernel<<<(GCN_M + 255) / 256, 256, 0, stream>>>(cnt, GCN_M);
    hist_kernel<<<edge_grid, 256, 0, stream>>>(rows, cols, cnt, GCN_E);
    scan1_kernel<<<SCAN_BLKS, 256, 0, stream>>>(cnt, rp, bsum);
    scan2_kernel<<<1, 64, 0, stream>>>(bsum, SCAN_BLKS);
    scan3_kernel<<<SCAN_BLKS, 256, 0, stream>>>(rp, cur, bsum);
    scatter_kernel<<<edge_grid, 256, 0, stream>>>(vals, rows, cols, cur, pval, pcol, GCN_E);

    const uint4* t4 = (const uint4*)t;

    // layer 1: x is [b][n][64] -> permuted read; intermediates in [n][512]
    gemm_relu_lds<<<gemm_grid, 256, 0, stream>>>(x, W0, t, 1);
    spmm_csr_bf16<<<spmm_grid, 256, 0, stream>>>(t4, pval, pcol, rp, out, 0);

    // layer 2
    gemm_relu_lds<<<gemm_grid, 256, 0, stream>>>(out, W1, t, 0);
    spmm_csr_bf16<<<spmm_grid, 256, 0, stream>>>(t4, pval, pcol, rp, out, 0);

    // layer 3: final output in [b][n][64]
    gemm_relu_lds<<<gemm_grid, 256, 0, stream>>>(out, W2, t, 0);
    spmm_csr_bf16<<<spmm_grid, 256, 0, stream>>>(t4, pval, pcol, rp, out, 1);
}

// Round 11
// 128.631 us; speedup vs baseline: 2.2702x; 1.5598x over previous
//
#include <hip/hip_runtime.h>
#include <hip/hip_bf16.h>

// GCN block: 3 x { t = relu(h @ W^T); h' = A_coo @ t (per sample) }
// B=8, N=10000, D=64, E=160000.
//
// Round 11:
//  - gemm -> MFMA (mfma_f32_16x16x32_bf16). The VALU/LDS-broadcast gemm was
//    ~35-45us each (1024 broadcast ds_read_b128/block @ ~12cy on one LDS
//    pipe). MFMA block: 64x64 tile, 4 waves, 32 mfma + ~80 LDS instrs.
//    Layouts per m89/m91: A row=l&15,k=(l>>4)*8+j; B col=l&15 same k;
//    C/D col=l&15,row=(l>>4)*4+reg.
//  - W0/W1/W2 converted to bf16 once per launch (cvt_w kernel).
//  - Intermediate h' stored bf16 [n][512] in d_out (final spmm overwrites
//    d_out fully as f32 [b][n][64]). Halves spmm writes + gemm reads.
//  - CSR build (zero/hist/scan1-3/scatter, col-tile keyed) and spmm gather
//    loop unchanged from round 10.

#define GCN_B 8
#define GCN_N 10000
#define GCN_D 64
#define GCN_E 160000
#define GCN_BN (GCN_B * GCN_N)
#define GCN_T 4
#define GCN_M (GCN_N * GCN_T)
#define SCAN_BLKS ((GCN_M + 1023) / 1024)   // 40

typedef __attribute__((ext_vector_type(8))) short short8v;
typedef __attribute__((ext_vector_type(4))) float float4v;

static __device__ __forceinline__ unsigned short f2bf(float f) {
    __hip_bfloat16 h = __float2bfloat16(f);
    return *reinterpret_cast<unsigned short*>(&h);
}

// ---------------- W f32 -> bf16 (once per launch) ----------------
__global__ __launch_bounds__(256) void cvt_w(
    const float* __restrict__ W0, const float* __restrict__ W1,
    const float* __restrict__ W2, unsigned short* __restrict__ Wb)
{
    int i = blockIdx.x * 256 + threadIdx.x;   // grid 48 -> 12288
    if (i < 4096)        Wb[i] = f2bf(W0[i]);
    else if (i < 8192)   Wb[i] = f2bf(W1[i - 4096]);
    else if (i < 12288)  Wb[i] = f2bf(W2[i - 8192]);
}

// ---------------- GEMM + ReLU via MFMA ----------------
// Computes t[g][f] = relu(sum_d h[g][d] * W[f][d]) for 64 g-rows per block.
// h input: f32_permuted=1 -> f32 [b][n][64] (row g reads b=g&7,n=g>>3);
//          f32_permuted=0 -> bf16 [g][64] flat (h' from spmm).
// t: bf16 [g][64] flat ([n][512]).
__global__ __launch_bounds__(256) void gemm_mfma(
    const void* __restrict__ hin,
    const unsigned short* __restrict__ Wb,   // [64][64] bf16
    unsigned short* __restrict__ t,
    int f32_permuted)
{
    __shared__ unsigned short hs[64 * 72];   // h tile, padded (bank stride 4)
    __shared__ unsigned short wsm[64 * 72];  // W tile, padded

    const int tid = threadIdx.x;
    const int g0 = blockIdx.x * 64;

    // ---- stage W: thread -> row=tid>>2, seg=tid&3 (16 shorts = 32B) ----
    {
        const int row = tid >> 2, seg = tid & 3;
        const uint4* src = reinterpret_cast<const uint4*>(Wb + row * 64 + seg * 16);
        uint4 a = src[0], b = src[1];
        *reinterpret_cast<uint4*>(&wsm[row * 72 + seg * 16])     = a;
        *reinterpret_cast<uint4*>(&wsm[row * 72 + seg * 16 + 8]) = b;
    }

    // ---- stage h tile (64 rows x 64 bf16) ----
    if (f32_permuted) {
        const int row = tid >> 2, seg = tid & 3;
        const int g = g0 + row;
        const int n = g >> 3, b = g & 7;
        const float4* src = reinterpret_cast<const float4*>(
            (const float*)hin + ((size_t)b * GCN_N + n) * 64 + seg * 16);
        float4 v0 = src[0], v1 = src[1], v2 = src[2], v3 = src[3];
        float vv[16] = {v0.x, v0.y, v0.z, v0.w, v1.x, v1.y, v1.z, v1.w,
                        v2.x, v2.y, v2.z, v2.w, v3.x, v3.y, v3.z, v3.w};
        unsigned int p[8];
#pragma unroll
        for (int j = 0; j < 8; ++j)
            p[j] = (unsigned int)f2bf(vv[2 * j]) |
                   ((unsigned int)f2bf(vv[2 * j + 1]) << 16);
        uint4 u0 = make_uint4(p[0], p[1], p[2], p[3]);
        uint4 u1 = make_uint4(p[4], p[5], p[6], p[7]);
        *reinterpret_cast<uint4*>(&hs[row * 72 + seg * 16])     = u0;
        *reinterpret_cast<uint4*>(&hs[row * 72 + seg * 16 + 8]) = u1;
    } else {
        const int row = tid >> 2, seg = tid & 3;
        const uint4* src = reinterpret_cast<const uint4*>(
            (const unsigned short*)hin + (size_t)(g0 + row) * 64 + seg * 16);
        uint4 a = src[0], b = src[1];
        *reinterpret_cast<uint4*>(&hs[row * 72 + seg * 16])     = a;
        *reinterpret_cast<uint4*>(&hs[row * 72 + seg * 16 + 8]) = b;
    }

    __syncthreads();

    const int w = tid >> 6;          // wave 0..3 -> rows w*16..w*16+15
    const int l = tid & 63;
    const int rbase = w * 16;
    const int arow = rbase + (l & 15);
    const int koff = (l >> 4) * 8;

    float4v acc[4];
#pragma unroll
    for (int nt = 0; nt < 4; ++nt) acc[nt] = (float4v){0.f, 0.f, 0.f, 0.f};

#pragma unroll
    for (int kc = 0; kc < 2; ++kc) {
        short8v afrag = *reinterpret_cast<const short8v*>(
            &hs[arow * 72 + kc * 32 + koff]);
#pragma unroll
        for (int nt = 0; nt < 4; ++nt) {
            short8v bfrag = *reinterpret_cast<const short8v*>(
                &wsm[(nt * 16 + (l & 15)) * 72 + kc * 32 + koff]);
            acc[nt] = __builtin_amdgcn_mfma_f32_16x16x32_bf16(
                afrag, bfrag, acc[nt], 0, 0, 0);
        }
    }

    // ---- epilogue: relu + bf16 store. C/D: col=l&15, row=(l>>4)*4+reg ----
    const int crow = rbase + (l >> 4) * 4;
    const int col = l & 15;
#pragma unroll
    for (int nt = 0; nt < 4; ++nt) {
#pragma unroll
        for (int r4 = 0; r4 < 4; ++r4) {
            float v = fmaxf(acc[nt][r4], 0.0f);
            t[(size_t)(g0 + crow + r4) * 64 + nt * 16 + col] = f2bf(v);
        }
    }
}

// ---------------- CSR build (keyed on row*4 + col_tile) ----------------
__global__ __launch_bounds__(256) void zero_kernel(int* __restrict__ p, int n)
{
    int i = blockIdx.x * 256 + threadIdx.x;
    if (i < n) p[i] = 0;
}

__global__ __launch_bounds__(256) void hist_kernel(
    const int* __restrict__ rows, const int* __restrict__ cols,
    int* __restrict__ cnt, int E)
{
    int e = blockIdx.x * 256 + threadIdx.x;
    if (e >= E) return;
    int tile = (unsigned)cols[e] / 2500u;
    atomicAdd(&cnt[rows[e] * GCN_T + tile], 1);
}

__global__ __launch_bounds__(256) void scan1_kernel(
    const int* __restrict__ cnt, int* __restrict__ rp, int* __restrict__ bsum)
{
    __shared__ int s[1024];
    __shared__ int part[256];
    const int tid = threadIdx.x;
    const int base = blockIdx.x * 1024;

#pragma unroll
    for (int k = 0; k < 4; ++k) {
        int idx = base + k * 256 + tid;
        s[k * 256 + tid] = (idx < GCN_M) ? cnt[idx] : 0;
    }
    __syncthreads();

    int l0 = s[tid * 4 + 0], l1 = s[tid * 4 + 1];
    int l2 = s[tid * 4 + 2], l3 = s[tid * 4 + 3];
    int ls = l0 + l1 + l2 + l3;
    part[tid] = ls;
    __syncthreads();
    for (int off = 1; off < 256; off <<= 1) {
        int add = (tid >= off) ? part[tid - off] : 0;
        __syncthreads();
        part[tid] += add;
        __syncthreads();
    }
    int run = part[tid] - ls;
    s[tid * 4 + 0] = run; run += l0;
    s[tid * 4 + 1] = run; run += l1;
    s[tid * 4 + 2] = run; run += l2;
    s[tid * 4 + 3] = run;
    if (tid == 255) bsum[blockIdx.x] = part[255];
    __syncthreads();

#pragma unroll
    for (int k = 0; k < 4; ++k) {
        int idx = base + k * 256 + tid;
        if (idx < GCN_M) rp[idx] = s[k * 256 + tid];
    }
}

__global__ __launch_bounds__(64) void scan2_kernel(int* __restrict__ bsum, int nb)
{
    const int tid = threadIdx.x;
    int x = (tid < nb) ? bsum[tid] : 0;
    int v = x;
    for (int off = 1; off < 64; off <<= 1) {
        int u = __shfl_up(v, off, 64);
        if (tid >= off) v += u;
    }
    if (tid < nb) bsum[tid] = v - x;
}

__global__ __launch_bounds__(256) void scan3_kernel(
    int* __restrict__ rp, int* __restrict__ cur, const int* __restrict__ bsum)
{
    const int base = blockIdx.x * 1024;
    const int off = bsum[blockIdx.x];
#pragma unroll
    for (int k = 0; k < 4; ++k) {
        int idx = base + k * 256 + threadIdx.x;
        if (idx < GCN_M) {
            int v = rp[idx] + off;
            rp[idx] = v;
            cur[idx] = v;
        }
    }
    if (blockIdx.x == 0 && threadIdx.x == 0) rp[GCN_M] = GCN_E;
}

__global__ __launch_bounds__(256) void scatter_kernel(
    const float* __restrict__ vals, const int* __restrict__ rows,
    const int* __restrict__ cols, int* __restrict__ cur,
    float* __restrict__ pval, int* __restrict__ pcol, int E)
{
    int e = blockIdx.x * 256 + threadIdx.x;
    if (e >= E) return;
    int c = cols[e];
    int tile = (unsigned)c / 2500u;
    int pos = atomicAdd(&cur[rows[e] * GCN_T + tile], 1);
    pval[pos] = vals[e];
    pcol[pos] = c;
}

// ---------------- CSR SpMM (bf16 gather, f32 accumulate) ----------------
// t: [N][64] uint4 (512 bf16/row). Lane holds elements [lane*8, lane*8+8).
// final_layout 0: write bf16 [n][512] to outb. 1: write f32 [b][n][64] to outf.
__global__ __launch_bounds__(256) void spmm_csr_bf16(
    const uint4* __restrict__ t4,
    const float* __restrict__ pval,
    const int* __restrict__ pcol,
    const int* __restrict__ rp,        // [N*4+1]
    unsigned short* __restrict__ outb,
    float* __restrict__ outf,
    int final_layout)
{
    const int r = (blockIdx.x * 256 + threadIdx.x) >> 6;
    const int lane = threadIdx.x & 63;
    if (r >= GCN_N) return;

    const int beg = rp[r * GCN_T];
    const int end = rp[r * GCN_T + GCN_T];

    float a[8];
#pragma unroll
    for (int i = 0; i < 8; ++i) a[i] = 0.f;

#pragma unroll 4
    for (int j = beg; j < end; ++j) {
        const float v = pval[j];
        const int c = pcol[j];
        uint4 u = t4[(size_t)c * 64 + lane];
        a[0] += v * __uint_as_float(u.x << 16);
        a[1] += v * __uint_as_float(u.x & 0xffff0000u);
        a[2] += v * __uint_as_float(u.y << 16);
        a[3] += v * __uint_as_float(u.y & 0xffff0000u);
        a[4] += v * __uint_as_float(u.z << 16);
        a[5] += v * __uint_as_float(u.z & 0xffff0000u);
        a[6] += v * __uint_as_float(u.w << 16);
        a[7] += v * __uint_as_float(u.w & 0xffff0000u);
    }

    if (!final_layout) {
        unsigned int p[4];
#pragma unroll
        for (int k = 0; k < 4; ++k)
            p[k] = (unsigned int)f2bf(a[2 * k]) |
                   ((unsigned int)f2bf(a[2 * k + 1]) << 16);
        uint4 o = make_uint4(p[0], p[1], p[2], p[3]);
        *reinterpret_cast<uint4*>(outb + (size_t)r * 512 + lane * 8) = o;
    } else {
        const int b = lane >> 3;
        const int d0 = (lane & 7) * 8;
        float* op = outf + ((size_t)b * GCN_N + r) * 64 + d0;
        *reinterpret_cast<float4*>(op)     = make_float4(a[0], a[1], a[2], a[3]);
        *reinterpret_cast<float4*>(op + 4) = make_float4(a[4], a[5], a[6], a[7]);
    }
}

extern "C" void kernel_launch(void* const* d_in, const int* in_sizes, int n_in,
                              void* d_out, int out_size, void* d_ws, size_t ws_size,
                              hipStream_t stream) {
    const float* x    = (const float*)d_in[0];
    const float* W0   = (const float*)d_in[1];
    const float* W1   = (const float*)d_in[2];
    const float* W2   = (const float*)d_in[3];
    const float* vals = (const float*)d_in[4];
    const int*   rows = (const int*)d_in[5];
    const int*   cols = (const int*)d_in[6];

    const size_t t_bytes = (size_t)GCN_BN * GCN_D * 2;   // bf16: 10,240,000

    char* ws = (char*)d_ws;
    unsigned short* t = (unsigned short*)ws;
    size_t off = (t_bytes + 255) / 256 * 256;
    int*   rp   = (int*)(ws + off); off += ((GCN_M + 1) * 4 + 255) / 256 * 256;
    int*   cur  = (int*)(ws + off); off += (GCN_M * 4 + 255) / 256 * 256;
    int*   cnt  = (int*)(ws + off); off += (GCN_M * 4 + 255) / 256 * 256;
    int*   bsum = (int*)(ws + off); off += (SCAN_BLKS * 4 + 255) / 256 * 256;
    float* pval = (float*)(ws + off); off += GCN_E * 4;
    int*   pcol = (int*)(ws + off); off += GCN_E * 4;
    unsigned short* Wb = (unsigned short*)(ws + off); off += 3 * 4096 * 2;

    // h' bf16 ping-pong lives in d_out (first 10.24MB); final spmm overwrites
    // all of d_out as f32 [b][n][64].
    unsigned short* hprime = (unsigned short*)d_out;
    float* outf = (float*)d_out;

    const int gemm_grid = GCN_BN / 64;                // 1250
    const int edge_grid = (GCN_E + 255) / 256;        // 625
    const int spmm_grid = (GCN_N * 64 + 255) / 256;   // 2500

    // Build col-tile-ordered CSR once; reused by all 3 layers.
    zero_kernel<<<(GCN_M + 255) / 256, 256, 0, stream>>>(cnt, GCN_M);
    hist_kernel<<<edge_grid, 256, 0, stream>>>(rows, cols, cnt, GCN_E);
    scan1_kernel<<<SCAN_BLKS, 256, 0, stream>>>(cnt, rp, bsum);
    scan2_kernel<<<1, 64, 0, stream>>>(bsum, SCAN_BLKS);
    scan3_kernel<<<SCAN_BLKS, 256, 0, stream>>>(rp, cur, bsum);
    scatter_kernel<<<edge_grid, 256, 0, stream>>>(vals, rows, cols, cur, pval, pcol, GCN_E);
    cvt_w<<<48, 256, 0, stream>>>(W0, W1, W2, Wb);

    const uint4* t4 = (const uint4*)t;

    // layer 1: x f32 [b][n][64] -> t bf16; spmm -> h' bf16 [n][512]
    gemm_mfma<<<gemm_grid, 256, 0, stream>>>(x, Wb, t, 1);
    spmm_csr_bf16<<<spmm_grid, 256, 0, stream>>>(t4, pval, pcol, rp, hprime, outf, 0);

    // layer 2
    gemm_mfma<<<gemm_grid, 256, 0, stream>>>(hprime, Wb + 4096, t, 0);
    spmm_csr_bf16<<<spmm_grid, 256, 0, stream>>>(t4, pval, pcol, rp, hprime, outf, 0);

    // layer 3: final output f32 [b][n][64]
    gemm_mfma<<<gemm_grid, 256, 0, stream>>>(hprime, Wb + 8192, t, 0);
    spmm_csr_bf16<<<spmm_grid, 256, 0, stream>>>(t4, pval, pcol, rp, hprime, outf, 1);
}

// Round 12
// 119.393 us; speedup vs baseline: 2.4459x; 1.0774x over previous
//
#include <hip/hip_runtime.h>
#include <hip/hip_bf16.h>

// GCN block: 3 x { t = relu(h @ W^T); h' = A_coo @ t (per sample) }
// B=8, N=10000, D=64, E=160000.
//
// Round 12:
//  - spmm_gemm_fused: 512-thr block (8 waves). Wave w gathers row r=bid*8+w's
//    edges (bf16 table, f32 accum, unroll 8), packs h' bf16 straight into the
//    LDS tile, one barrier, then the round-11-verified 16x16x32 MFMA gemm
//    (8 waves = 4 row-quadrants x 2 col-halves) writes t_next. Kills 2x
//    (h' global write + re-read) = ~41MB and 2 launches.
//  - Buffers: gemm1 x->tA(ws); F1 tA->t2(d_out bf16); F2 t2->tA(ws);
//    spmm3 tA -> d_out f32 (full overwrite). No aliasing; ws ~12MB.
//  - CSR build (col-tile keyed, T=4) unchanged; spmm unroll 4->8.

#define GCN_B 8
#define GCN_N 10000
#define GCN_D 64
#define GCN_E 160000
#define GCN_BN (GCN_B * GCN_N)
#define GCN_T 4
#define GCN_M (GCN_N * GCN_T)
#define SCAN_BLKS ((GCN_M + 1023) / 1024)   // 40

typedef __attribute__((ext_vector_type(8))) short short8v;
typedef __attribute__((ext_vector_type(4))) float float4v;

static __device__ __forceinline__ unsigned short f2bf(float f) {
    __hip_bfloat16 h = __float2bfloat16(f);
    return *reinterpret_cast<unsigned short*>(&h);
}

// ---------------- W f32 -> bf16 (once per launch) ----------------
__global__ __launch_bounds__(256) void cvt_w(
    const float* __restrict__ W0, const float* __restrict__ W1,
    const float* __restrict__ W2, unsigned short* __restrict__ Wb)
{
    int i = blockIdx.x * 256 + threadIdx.x;   // grid 48 -> 12288
    if (i < 4096)        Wb[i] = f2bf(W0[i]);
    else if (i < 8192)   Wb[i] = f2bf(W1[i - 4096]);
    else if (i < 12288)  Wb[i] = f2bf(W2[i - 8192]);
}

// ---------------- layer-1 GEMM + ReLU via MFMA (f32 x input) ----------------
__global__ __launch_bounds__(256) void gemm_mfma(
    const float* __restrict__ hin,           // f32 [b][n][64]
    const unsigned short* __restrict__ Wb,   // [64][64] bf16
    unsigned short* __restrict__ t)          // bf16 [n][512] flat
{
    __shared__ unsigned short hs[64 * 72];
    __shared__ unsigned short wsm[64 * 72];

    const int tid = threadIdx.x;
    const int g0 = blockIdx.x * 64;

    {   // stage W: row=tid>>2, seg=tid&3 (16 shorts = 32B)
        const int row = tid >> 2, seg = tid & 3;
        const uint4* src = reinterpret_cast<const uint4*>(Wb + row * 64 + seg * 16);
        uint4 a = src[0], b = src[1];
        *reinterpret_cast<uint4*>(&wsm[row * 72 + seg * 16])     = a;
        *reinterpret_cast<uint4*>(&wsm[row * 72 + seg * 16 + 8]) = b;
    }
    {   // stage h tile: f32 permuted read, convert to bf16
        const int row = tid >> 2, seg = tid & 3;
        const int g = g0 + row;
        const int n = g >> 3, b = g & 7;
        const float4* src = reinterpret_cast<const float4*>(
            hin + ((size_t)b * GCN_N + n) * 64 + seg * 16);
        float4 v0 = src[0], v1 = src[1], v2 = src[2], v3 = src[3];
        float vv[16] = {v0.x, v0.y, v0.z, v0.w, v1.x, v1.y, v1.z, v1.w,
                        v2.x, v2.y, v2.z, v2.w, v3.x, v3.y, v3.z, v3.w};
        unsigned int p[8];
#pragma unroll
        for (int j = 0; j < 8; ++j)
            p[j] = (unsigned int)f2bf(vv[2 * j]) |
                   ((unsigned int)f2bf(vv[2 * j + 1]) << 16);
        *reinterpret_cast<uint4*>(&hs[row * 72 + seg * 16]) =
            make_uint4(p[0], p[1], p[2], p[3]);
        *reinterpret_cast<uint4*>(&hs[row * 72 + seg * 16 + 8]) =
            make_uint4(p[4], p[5], p[6], p[7]);
    }
    __syncthreads();

    const int w = tid >> 6;
    const int l = tid & 63;
    const int rbase = w * 16;
    const int arow = rbase + (l & 15);
    const int koff = (l >> 4) * 8;

    float4v acc[4];
#pragma unroll
    for (int nt = 0; nt < 4; ++nt) acc[nt] = (float4v){0.f, 0.f, 0.f, 0.f};

#pragma unroll
    for (int kc = 0; kc < 2; ++kc) {
        short8v afrag = *reinterpret_cast<const short8v*>(
            &hs[arow * 72 + kc * 32 + koff]);
#pragma unroll
        for (int nt = 0; nt < 4; ++nt) {
            short8v bfrag = *reinterpret_cast<const short8v*>(
                &wsm[(nt * 16 + (l & 15)) * 72 + kc * 32 + koff]);
            acc[nt] = __builtin_amdgcn_mfma_f32_16x16x32_bf16(
                afrag, bfrag, acc[nt], 0, 0, 0);
        }
    }

    const int crow = rbase + (l >> 4) * 4;
    const int col = l & 15;
#pragma unroll
    for (int nt = 0; nt < 4; ++nt)
#pragma unroll
        for (int r4 = 0; r4 < 4; ++r4)
            t[(size_t)(g0 + crow + r4) * 64 + nt * 16 + col] =
                f2bf(fmaxf(acc[nt][r4], 0.0f));
}

// ---------------- fused SpMM -> GEMM + ReLU ----------------
// Wave w gathers n-row r = bid*8+w (h'[r][512] f32 accum), packs bf16 into
// hs tile (g_local = w*8+b), then 8-wave MFMA computes t_next = relu(h' W^T).
__global__ __launch_bounds__(512) void spmm_gemm_fused(
    const uint4* __restrict__ t4_in,         // gather table [N*64] uint4
    const float* __restrict__ pval,
    const int* __restrict__ pcol,
    const int* __restrict__ rp,              // [N*4+1]
    const unsigned short* __restrict__ Wb,   // next layer W, bf16
    unsigned short* __restrict__ t_out)      // bf16 [n][512] flat
{
    __shared__ unsigned short hs[64 * 72];
    __shared__ unsigned short wsm[64 * 72];

    const int tid = threadIdx.x;
    const int g0 = blockIdx.x * 64;

    {   // stage W: 512 threads x one uint4 (8 shorts)
        const int row = tid >> 3, seg = tid & 7;
        uint4 v = *reinterpret_cast<const uint4*>(Wb + row * 64 + seg * 8);
        *reinterpret_cast<uint4*>(&wsm[row * 72 + seg * 8]) = v;
    }

    const int w = tid >> 6;          // 0..7
    const int lane = tid & 63;
    const int r = blockIdx.x * 8 + w;

    // ---- spmm for row r ----
    const int beg = rp[r * GCN_T];
    const int end = rp[r * GCN_T + GCN_T];

    float a[8];
#pragma unroll
    for (int i = 0; i < 8; ++i) a[i] = 0.f;

#pragma unroll 8
    for (int j = beg; j < end; ++j) {
        const float v = pval[j];
        const int c = pcol[j];
        uint4 u = t4_in[(size_t)c * 64 + lane];
        a[0] += v * __uint_as_float(u.x << 16);
        a[1] += v * __uint_as_float(u.x & 0xffff0000u);
        a[2] += v * __uint_as_float(u.y << 16);
        a[3] += v * __uint_as_float(u.y & 0xffff0000u);
        a[4] += v * __uint_as_float(u.z << 16);
        a[5] += v * __uint_as_float(u.z & 0xffff0000u);
        a[6] += v * __uint_as_float(u.w << 16);
        a[7] += v * __uint_as_float(u.w & 0xffff0000u);
    }

    {   // pack h'[r] bf16 into hs: g_local = w*8 + (lane>>3), col (lane&7)*8
        unsigned int p[4];
#pragma unroll
        for (int k = 0; k < 4; ++k)
            p[k] = (unsigned int)f2bf(a[2 * k]) |
                   ((unsigned int)f2bf(a[2 * k + 1]) << 16);
        *reinterpret_cast<uint4*>(
            &hs[(w * 8 + (lane >> 3)) * 72 + (lane & 7) * 8]) =
            make_uint4(p[0], p[1], p[2], p[3]);
    }
    __syncthreads();

    // ---- MFMA: quadrant q = w>>1 (16 rows), col-half pr = w&1 (2 nt) ----
    const int q = w >> 1, pr = w & 1;
    const int arow = q * 16 + (lane & 15);
    const int koff = (lane >> 4) * 8;

    float4v acc[2];
    acc[0] = (float4v){0.f, 0.f, 0.f, 0.f};
    acc[1] = (float4v){0.f, 0.f, 0.f, 0.f};

#pragma unroll
    for (int kc = 0; kc < 2; ++kc) {
        short8v afrag = *reinterpret_cast<const short8v*>(
            &hs[arow * 72 + kc * 32 + koff]);
#pragma unroll
        for (int nt2 = 0; nt2 < 2; ++nt2) {
            const int nt = pr * 2 + nt2;
            short8v bfrag = *reinterpret_cast<const short8v*>(
                &wsm[(nt * 16 + (lane & 15)) * 72 + kc * 32 + koff]);
            acc[nt2] = __builtin_amdgcn_mfma_f32_16x16x32_bf16(
                afrag, bfrag, acc[nt2], 0, 0, 0);
        }
    }

    const int crow = q * 16 + (lane >> 4) * 4;
    const int col = lane & 15;
#pragma unroll
    for (int nt2 = 0; nt2 < 2; ++nt2) {
        const int nt = pr * 2 + nt2;
#pragma unroll
        for (int r4 = 0; r4 < 4; ++r4)
            t_out[(size_t)(g0 + crow + r4) * 64 + nt * 16 + col] =
                f2bf(fmaxf(acc[nt2][r4], 0.0f));
    }
}

// ---------------- CSR build (keyed on row*4 + col_tile) ----------------
__global__ __launch_bounds__(256) void zero_kernel(int* __restrict__ p, int n)
{
    int i = blockIdx.x * 256 + threadIdx.x;
    if (i < n) p[i] = 0;
}

__global__ __launch_bounds__(256) void hist_kernel(
    const int* __restrict__ rows, const int* __restrict__ cols,
    int* __restrict__ cnt, int E)
{
    int e = blockIdx.x * 256 + threadIdx.x;
    if (e >= E) return;
    int tile = (unsigned)cols[e] / 2500u;
    atomicAdd(&cnt[rows[e] * GCN_T + tile], 1);
}

__global__ __launch_bounds__(256) void scan1_kernel(
    const int* __restrict__ cnt, int* __restrict__ rp, int* __restrict__ bsum)
{
    __shared__ int s[1024];
    __shared__ int part[256];
    const int tid = threadIdx.x;
    const int base = blockIdx.x * 1024;

#pragma unroll
    for (int k = 0; k < 4; ++k) {
        int idx = base + k * 256 + tid;
        s[k * 256 + tid] = (idx < GCN_M) ? cnt[idx] : 0;
    }
    __syncthreads();

    int l0 = s[tid * 4 + 0], l1 = s[tid * 4 + 1];
    int l2 = s[tid * 4 + 2], l3 = s[tid * 4 + 3];
    int ls = l0 + l1 + l2 + l3;
    part[tid] = ls;
    __syncthreads();
    for (int off = 1; off < 256; off <<= 1) {
        int add = (tid >= off) ? part[tid - off] : 0;
        __syncthreads();
        part[tid] += add;
        __syncthreads();
    }
    int run = part[tid] - ls;
    s[tid * 4 + 0] = run; run += l0;
    s[tid * 4 + 1] = run; run += l1;
    s[tid * 4 + 2] = run; run += l2;
    s[tid * 4 + 3] = run;
    if (tid == 255) bsum[blockIdx.x] = part[255];
    __syncthreads();

#pragma unroll
    for (int k = 0; k < 4; ++k) {
        int idx = base + k * 256 + tid;
        if (idx < GCN_M) rp[idx] = s[k * 256 + tid];
    }
}

__global__ __launch_bounds__(64) void scan2_kernel(int* __restrict__ bsum, int nb)
{
    const int tid = threadIdx.x;
    int x = (tid < nb) ? bsum[tid] : 0;
    int v = x;
    for (int off = 1; off < 64; off <<= 1) {
        int u = __shfl_up(v, off, 64);
        if (tid >= off) v += u;
    }
    if (tid < nb) bsum[tid] = v - x;
}

__global__ __launch_bounds__(256) void scan3_kernel(
    int* __restrict__ rp, int* __restrict__ cur, const int* __restrict__ bsum)
{
    const int base = blockIdx.x * 1024;
    const int off = bsum[blockIdx.x];
#pragma unroll
    for (int k = 0; k < 4; ++k) {
        int idx = base + k * 256 + threadIdx.x;
        if (idx < GCN_M) {
            int v = rp[idx] + off;
            rp[idx] = v;
            cur[idx] = v;
        }
    }
    if (blockIdx.x == 0 && threadIdx.x == 0) rp[GCN_M] = GCN_E;
}

__global__ __launch_bounds__(256) void scatter_kernel(
    const float* __restrict__ vals, const int* __restrict__ rows,
    const int* __restrict__ cols, int* __restrict__ cur,
    float* __restrict__ pval, int* __restrict__ pcol, int E)
{
    int e = blockIdx.x * 256 + threadIdx.x;
    if (e >= E) return;
    int c = cols[e];
    int tile = (unsigned)c / 2500u;
    int pos = atomicAdd(&cur[rows[e] * GCN_T + tile], 1);
    pval[pos] = vals[e];
    pcol[pos] = c;
}

// ---------------- final standalone SpMM (f32 [b][n][64] out) ----------------
__global__ __launch_bounds__(256) void spmm_final(
    const uint4* __restrict__ t4,
    const float* __restrict__ pval,
    const int* __restrict__ pcol,
    const int* __restrict__ rp,
    float* __restrict__ outf)
{
    const int r = (blockIdx.x * 256 + threadIdx.x) >> 6;
    const int lane = threadIdx.x & 63;
    if (r >= GCN_N) return;

    const int beg = rp[r * GCN_T];
    const int end = rp[r * GCN_T + GCN_T];

    float a[8];
#pragma unroll
    for (int i = 0; i < 8; ++i) a[i] = 0.f;

#pragma unroll 8
    for (int j = beg; j < end; ++j) {
        const float v = pval[j];
        const int c = pcol[j];
        uint4 u = t4[(size_t)c * 64 + lane];
        a[0] += v * __uint_as_float(u.x << 16);
        a[1] += v * __uint_as_float(u.x & 0xffff0000u);
        a[2] += v * __uint_as_float(u.y << 16);
        a[3] += v * __uint_as_float(u.y & 0xffff0000u);
        a[4] += v * __uint_as_float(u.z << 16);
        a[5] += v * __uint_as_float(u.z & 0xffff0000u);
        a[6] += v * __uint_as_float(u.w << 16);
        a[7] += v * __uint_as_float(u.w & 0xffff0000u);
    }

    const int b = lane >> 3;
    const int d0 = (lane & 7) * 8;
    float* op = outf + ((size_t)b * GCN_N + r) * 64 + d0;
    *reinterpret_cast<float4*>(op)     = make_float4(a[0], a[1], a[2], a[3]);
    *reinterpret_cast<float4*>(op + 4) = make_float4(a[4], a[5], a[6], a[7]);
}

extern "C" void kernel_launch(void* const* d_in, const int* in_sizes, int n_in,
                              void* d_out, int out_size, void* d_ws, size_t ws_size,
                              hipStream_t stream) {
    const float* x    = (const float*)d_in[0];
    const float* W0   = (const float*)d_in[1];
    const float* W1   = (const float*)d_in[2];
    const float* W2   = (const float*)d_in[3];
    const float* vals = (const float*)d_in[4];
    const int*   rows = (const int*)d_in[5];
    const int*   cols = (const int*)d_in[6];

    const size_t t_bytes = (size_t)GCN_BN * GCN_D * 2;   // bf16: 10,240,000

    char* ws = (char*)d_ws;
    unsigned short* tA = (unsigned short*)ws;            // in d_ws
    size_t off = (t_bytes + 255) / 256 * 256;
    int*   rp   = (int*)(ws + off); off += ((GCN_M + 1) * 4 + 255) / 256 * 256;
    int*   cur  = (int*)(ws + off); off += (GCN_M * 4 + 255) / 256 * 256;
    int*   cnt  = (int*)(ws + off); off += (GCN_M * 4 + 255) / 256 * 256;
    int*   bsum = (int*)(ws + off); off += (SCAN_BLKS * 4 + 255) / 256 * 256;
    float* pval = (float*)(ws + off); off += GCN_E * 4;
    int*   pcol = (int*)(ws + off); off += GCN_E * 4;
    unsigned short* Wb = (unsigned short*)(ws + off); off += 3 * 4096 * 2;

    unsigned short* t2 = (unsigned short*)d_out;         // bf16 scratch in d_out
    float* outf = (float*)d_out;                         // final f32 output

    const int gemm_grid = GCN_BN / 64;                // 1250
    const int edge_grid = (GCN_E + 255) / 256;        // 625
    const int spmm_grid = (GCN_N * 64 + 255) / 256;   // 2500

    // Build col-tile-ordered CSR once; reused by all 3 layers.
    zero_kernel<<<(GCN_M + 255) / 256, 256, 0, stream>>>(cnt, GCN_M);
    hist_kernel<<<edge_grid, 256, 0, stream>>>(rows, cols, cnt, GCN_E);
    scan1_kernel<<<SCAN_BLKS, 256, 0, stream>>>(cnt, rp, bsum);
    scan2_kernel<<<1, 64, 0, stream>>>(bsum, SCAN_BLKS);
    scan3_kernel<<<SCAN_BLKS, 256, 0, stream>>>(rp, cur, bsum);
    scatter_kernel<<<edge_grid, 256, 0, stream>>>(vals, rows, cols, cur, pval, pcol, GCN_E);
    cvt_w<<<48, 256, 0, stream>>>(W0, W1, W2, Wb);

    // layer 1: x -> t1 (tA)
    gemm_mfma<<<gemm_grid, 256, 0, stream>>>(x, Wb, tA);
    // layer 1 spmm + layer 2 gemm: tA -> t2 (d_out, bf16)
    spmm_gemm_fused<<<gemm_grid, 512, 0, stream>>>(
        (const uint4*)tA, pval, pcol, rp, Wb + 4096, t2);
    // layer 2 spmm + layer 3 gemm: t2 -> t3 (tA)
    spmm_gemm_fused<<<gemm_grid, 512, 0, stream>>>(
        (const uint4*)t2, pval, pcol, rp, Wb + 8192, tA);
    // layer 3 spmm: tA -> d_out f32 [b][n][64] (full overwrite)
    spmm_final<<<spmm_grid, 256, 0, stream>>>((const uint4*)tA, pval, pcol, rp, outf);
}